// Round 1
// 529.344 us; speedup vs baseline: 1.0760x; 1.0760x over previous
//
#include <hip/hip_runtime.h>
#include <stdint.h>
#include <stddef.h>

#define DIN    512
#define BGR    1024
#define NGATE  2048   // 4*DIN
#define KQ     1024   // 2*DIN (q_star width)
#define DOUT   512
#define TSTEPS 6

typedef unsigned short ushort_t;
typedef short bf16x8 __attribute__((ext_vector_type(8)));
typedef unsigned short u16x8 __attribute__((ext_vector_type(8)));
typedef float f32x4 __attribute__((ext_vector_type(4)));

__device__ __forceinline__ float b2f(unsigned short u) {
    unsigned int i = ((unsigned int)u) << 16;
    float f;
    __builtin_memcpy(&f, &i, 4);
    return f;
}

__device__ __forceinline__ unsigned short f2b(float f) {
    unsigned int i;
    __builtin_memcpy(&i, &f, 4);
    unsigned int lsb = (i >> 16) & 1u;
    i += 0x7fffu + lsb;   // round-to-nearest-even
    return (unsigned short)(i >> 16);
}

__device__ __forceinline__ float fast_sigmoid(float v) {
    return 1.f / (1.f + __expf(-v));
}

__device__ __forceinline__ float fast_tanh(float v) {
    float t = fabsf(v);
    float e = __expf(-2.f * t);
    float r = (1.f - e) / (1.f + e);
    return v < 0.f ? -r : r;
}

// ---------------------------------------------------------------------------
// Dtype probe: flags[t]=1 if tensor t is f32, 0 if bf16.
// ---------------------------------------------------------------------------
__global__ void probe_dtypes(const ushort_t* x, const ushort_t* Wih,
                             const ushort_t* Whh, const ushort_t* bih,
                             const ushort_t* bhh, const ushort_t* Wpost,
                             const ushort_t* bpost, int* flags)
{
    __shared__ int cnt[7];
    const int tid = threadIdx.x;
    if (tid < 7) cnt[tid] = 0;
    __syncthreads();
    const int t = tid >> 5;
    const int l = tid & 31;
    if (t < 7) {
        const ushort_t* p = (t == 0) ? x : (t == 1) ? Wih : (t == 2) ? Whh
                          : (t == 3) ? bih : (t == 4) ? bhh
                          : (t == 5) ? Wpost : bpost;
        int good = 0;
        for (int i = 0; i < 4; i++) {
            ushort_t u = p[(l * 4 + i) * 2];
            int ex = (u >> 7) & 0xFF;
            if (ex == 0 || (ex >= 96 && ex <= 143)) good++;
        }
        atomicAdd(&cnt[t], good);
    }
    __syncthreads();
    if (tid < 7) flags[tid] = (cnt[tid] < 96) ? 1 : 0;
}

#define BM 64
#define BN 64
#define BK 32

// ---------------------------------------------------------------------------
// Fused z-GEMM + LSTM cell. Weights in gate-interleaved layout Wp2:
//   nn = (d>>4)*64 + g*16 + (d&15)  maps original row n = g*512 + d.
// Block = 64 rows x 64 gate-cols (= one 16-dim block x 4 gates), K = 1024.
// 4 waves, wave w owns rows w*16..w*16+15; acc[ni] = gate ni.
// Epilogue: each lane holds zi,zf,zg,zo for (row, dim) -> c,h in-register;
// writes c (f32) and H (f32). z never touches memory.
// Staging software-pipelined: next K-tile global loads issued before compute.
// ---------------------------------------------------------------------------
__global__ __launch_bounds__(256)
void gemm_cell(const ushort_t* __restrict__ Ag,   // q_star [1024][1024] bf16
               const ushort_t* __restrict__ Wg,   // Wp2 [2048][1024] bf16
               const float* __restrict__ bias2,   // gate-interleaved bias
               float* __restrict__ c, float* __restrict__ H)
{
    __shared__ __align__(16) ushort_t As[BM * BK];
    __shared__ __align__(16) ushort_t Bs[BM * BK];

    const int tid  = threadIdx.x;
    const int lane = tid & 63;
    const int w    = tid >> 6;
    const int lrow = lane & 15;
    const int quad = lane >> 4;

    const int n0 = blockIdx.x * 64;   // Wp2 row block (dim-block * 64)
    const int m0 = blockIdx.y * BM;

    const int srow = tid >> 2;        // 0..63
    const int scol = (tid & 3) * 8;   // 0,8,16,24

    const ushort_t* aSrc = Ag + (size_t)(m0 + srow) * KQ + scol;
    const ushort_t* bSrc = Wg + (size_t)(n0 + srow) * KQ + scol;

    f32x4 acc[4];
#pragma unroll
    for (int ni = 0; ni < 4; ni++) acc[ni] = (f32x4){0.f, 0.f, 0.f, 0.f};

    bf16x8 av = *(const bf16x8*)(aSrc);
    bf16x8 bv = *(const bf16x8*)(bSrc);

    for (int kt = 0; kt < KQ; kt += BK) {
        __syncthreads();
        *(bf16x8*)&As[srow * BK + scol] = av;
        *(bf16x8*)&Bs[srow * BK + scol] = bv;
        if (kt + BK < KQ) {                      // prefetch next K-tile
            av = *(const bf16x8*)(aSrc + kt + BK);
            bv = *(const bf16x8*)(bSrc + kt + BK);
        }
        __syncthreads();

        bf16x8 af = *(const bf16x8*)&As[(w * 16 + lrow) * BK + quad * 8];
        bf16x8 bfr[4];
#pragma unroll
        for (int ni = 0; ni < 4; ni++)
            bfr[ni] = *(const bf16x8*)&Bs[(ni * 16 + lrow) * BK + quad * 8];
#pragma unroll
        for (int ni = 0; ni < 4; ni++)
            acc[ni] = __builtin_amdgcn_mfma_f32_16x16x32_bf16(
                af, bfr[ni], acc[ni], 0, 0, 0);
    }

    // ---- fused LSTM cell epilogue (D layout: row=quad*4+r, col=lrow) ----
    const int d   = blockIdx.x * 16 + lrow;
    const float bi = bias2[n0 + lrow];
    const float bf = bias2[n0 + 16 + lrow];
    const float bg = bias2[n0 + 32 + lrow];
    const float bo = bias2[n0 + 48 + lrow];
#pragma unroll
    for (int r = 0; r < 4; r++) {
        const int gm = m0 + w * 16 + quad * 4 + r;
        float zi = acc[0][r] + bi;
        float zf = acc[1][r] + bf;
        float zg = acc[2][r] + bg;
        float zo = acc[3][r] + bo;
        size_t off = (size_t)gm * DIN + d;
        float cc = c[off];
        cc = fast_sigmoid(zf) * cc + fast_sigmoid(zi) * fast_tanh(zg);
        float hh = fast_sigmoid(zo) * fast_tanh(cc);
        c[off] = cc;
        H[off] = hh;
    }
}

// ---------------------------------------------------------------------------
// Plain GEMM 64x64 tile (used once, for the final Wpost + relu).
// Same pipelined staging.
// ---------------------------------------------------------------------------
template <int MODE>
__global__ __launch_bounds__(256)
void gemm_bt(const ushort_t* __restrict__ Ag, const ushort_t* __restrict__ Bg,
             const float* __restrict__ bias, float* __restrict__ Cout,
             int M, int N, int K)
{
    __shared__ __align__(16) ushort_t As[BM * BK];
    __shared__ __align__(16) ushort_t Bs[BN * BK];

    const int tid  = threadIdx.x;
    const int lane = tid & 63;
    const int w    = tid >> 6;
    const int wr   = w >> 1;
    const int wc   = w & 1;
    const int lrow = lane & 15;
    const int quad = lane >> 4;

    const int n0 = blockIdx.x * BN;
    const int m0 = blockIdx.y * BM;

    const int srow = tid >> 2;
    const int scol = (tid & 3) * 8;

    const ushort_t* aSrc = Ag + (size_t)(m0 + srow) * K + scol;
    const ushort_t* bSrc = Bg + (size_t)(n0 + srow) * K + scol;

    f32x4 acc[2][2];
#pragma unroll
    for (int i = 0; i < 2; i++)
#pragma unroll
        for (int j = 0; j < 2; j++)
            acc[i][j] = (f32x4){0.f, 0.f, 0.f, 0.f};

    bf16x8 av = *(const bf16x8*)(aSrc);
    bf16x8 bv = *(const bf16x8*)(bSrc);

    for (int kt = 0; kt < K; kt += BK) {
        __syncthreads();
        *(bf16x8*)&As[srow * BK + scol] = av;
        *(bf16x8*)&Bs[srow * BK + scol] = bv;
        if (kt + BK < K) {
            av = *(const bf16x8*)(aSrc + kt + BK);
            bv = *(const bf16x8*)(bSrc + kt + BK);
        }
        __syncthreads();

        bf16x8 af[2], bfr[2];
#pragma unroll
        for (int mi = 0; mi < 2; mi++)
            af[mi] = *(const bf16x8*)&As[(wr * 32 + mi * 16 + lrow) * BK + quad * 8];
#pragma unroll
        for (int ni = 0; ni < 2; ni++)
            bfr[ni] = *(const bf16x8*)&Bs[(wc * 32 + ni * 16 + lrow) * BK + quad * 8];

#pragma unroll
        for (int mi = 0; mi < 2; mi++)
#pragma unroll
            for (int ni = 0; ni < 2; ni++)
                acc[mi][ni] = __builtin_amdgcn_mfma_f32_16x16x32_bf16(
                    af[mi], bfr[ni], acc[mi][ni], 0, 0, 0);
    }

#pragma unroll
    for (int mi = 0; mi < 2; mi++) {
#pragma unroll
        for (int ni = 0; ni < 2; ni++) {
#pragma unroll
            for (int r = 0; r < 4; r++) {
                int gm = m0 + wr * 32 + mi * 16 + quad * 4 + r;
                int gn = n0 + wc * 32 + ni * 16 + lrow;
                float v = acc[mi][ni][r] + bias[gn];
                if (MODE == 1) {
                    if (!(v > 0.f) && (v == v)) v = 0.f;   // NaN-transparent relu
                }
                Cout[(size_t)gm * N + gn] = v;
            }
        }
    }
}

// ---------------------------------------------------------------------------
// One-pass online-softmax attention (LSTM cell now lives in gemm_cell).
// Reads q = h from H (f32), copies it to A[:, :512] as bf16, writes r.
// XMODE 0: read bf16 from xb.  XMODE 1: t=0 — branch on flags[0], write xb.
// XMODE 2: fallback — branch read from x, no xb write.
// ---------------------------------------------------------------------------
template <int XMODE>
__global__ __launch_bounds__(256)
void attn_step(const ushort_t* __restrict__ xbsrc, const ushort_t* __restrict__ xraw,
               ushort_t* __restrict__ xbdst, const int* __restrict__ offs,
               const float* __restrict__ H, ushort_t* __restrict__ A,
               const int* __restrict__ flags)
{
    const int b    = blockIdx.x;
    const int tid  = threadIdx.x;
    const int lane = tid & 63;
    const int w    = tid >> 6;
    const int xf   = (XMODE == 0) ? 0 : flags[0];   // uniform

    __shared__ float accL[4][DIN];   // 8 KB
    __shared__ float mw[4], lw[4];

    // ---- q = h: copy to q_star (bf16) and load per-lane slice ----
    const float* hrow = H + (size_t)b * DIN;
    {
        const int d0 = tid * 2;
        A[(size_t)b * KQ + d0]     = f2b(hrow[d0]);
        A[(size_t)b * KQ + d0 + 1] = f2b(hrow[d0 + 1]);
    }
    f32x4 q0 = *(const f32x4*)(hrow + lane * 8);
    f32x4 q1 = *(const f32x4*)(hrow + lane * 8 + 4);
    float q8[8] = {q0[0], q0[1], q0[2], q0[3], q1[0], q1[1], q1[2], q1[3]};

    const int s  = offs[b];
    const int en = offs[b + 1];

    const float NEG_INF = -__builtin_inff();
    float m = NEG_INF, l = 0.f;
    float acc[8];
#pragma unroll
    for (int j = 0; j < 8; j++) acc[j] = 0.f;

    // lane covers dims [lane*8, lane*8+8)
    auto load_row = [&](int n, float* v) {
        if (XMODE == 0 || !xf) {
            const ushort_t* src = (XMODE == 0) ? xbsrc : xraw;
            u16x8 xv = *(const u16x8*)(src + (size_t)n * DIN + lane * 8);
#pragma unroll
            for (int j = 0; j < 8; j++) v[j] = b2f(xv[j]);
            if (XMODE == 1)
                *(u16x8*)(xbdst + (size_t)n * DIN + lane * 8) = xv;
        } else {
            const float* xp = (const float*)xraw;
            f32x4 v0 = *(const f32x4*)(xp + (size_t)n * DIN + lane * 8);
            f32x4 v1 = *(const f32x4*)(xp + (size_t)n * DIN + lane * 8 + 4);
#pragma unroll
            for (int j = 0; j < 4; j++) { v[j] = v0[j]; v[4 + j] = v1[j]; }
            if (XMODE == 1) {
                u16x8 o;
#pragma unroll
                for (int j = 0; j < 8; j++) o[j] = f2b(v[j]);
                *(u16x8*)(xbdst + (size_t)n * DIN + lane * 8) = o;
            }
        }
    };

    auto update = [&](float e, const float* xv) {
        float mn = fmaxf(m, e);
        float al = __expf(m - mn);    // first node: exp(-inf)=0
        float pp = __expf(e - mn);
        l = l * al + pp;
#pragma unroll
        for (int j = 0; j < 8; j++) acc[j] = acc[j] * al + pp * xv[j];
        m = mn;
    };

    // ---- pair-pipelined pass (rows n, n+4; prefetch n+8, n+12) ----
    float xa[8] = {0.f}, xc[8] = {0.f};
    int n = s + w;
    if (n < en)     load_row(n, xa);
    if (n + 4 < en) load_row(n + 4, xc);
    for (; n < en; n += 8) {
        float pa[8], pc[8];
        const int np = n + 8;
        if (np < en)     load_row(np, pa);
        if (np + 4 < en) load_row(np + 4, pc);

        float e1 = 0.f, e2 = 0.f;
#pragma unroll
        for (int j = 0; j < 8; j++) { e1 += q8[j] * xa[j]; e2 += q8[j] * xc[j]; }
#pragma unroll
        for (int off = 32; off > 0; off >>= 1) {
            e1 += __shfl_xor(e1, off, 64);
            e2 += __shfl_xor(e2, off, 64);
        }

        update(e1, xa);
        if (n + 4 < en) update(e2, xc);

#pragma unroll
        for (int j = 0; j < 8; j++) { xa[j] = pa[j]; xc[j] = pc[j]; }
    }

    // ---- merge 4 waves (flash combine) ----
    if (lane == 0) { mw[w] = m; lw[w] = l; }
#pragma unroll
    for (int j = 0; j < 8; j++) accL[w][lane * 8 + j] = acc[j];
    __syncthreads();

    const float M = fmaxf(fmaxf(mw[0], mw[1]), fmaxf(mw[2], mw[3]));
    const int d0 = tid * 2;
    float r0 = 0.f, r1 = 0.f, lt = 0.f;
#pragma unroll
    for (int ww = 0; ww < 4; ww++) {
        float mwv = mw[ww];
        float a = (mwv == NEG_INF) ? 0.f : __expf(mwv - M);
        lt += a * lw[ww];
        r0 += a * accL[ww][d0];
        r1 += a * accL[ww][d0 + 1];
    }
    float inv = lt > 0.f ? 1.f / lt : 0.f;   // empty graph -> r = 0
    A[(size_t)b * KQ + DIN + d0]     = f2b(r0 * inv);
    A[(size_t)b * KQ + DIN + d0 + 1] = f2b(r1 * inv);
}

// ---------------------------------------------------------------------------
// Prep: fused weight W' = Wih (+Whh on k<512), rows permuted to the
// gate-interleaved layout nn = (d>>4)*64 + g*16 + (d&15); bias likewise.
// Wpost -> bf16. All reads dtype-dispatched via flags.
// ---------------------------------------------------------------------------
__global__ void prep_weights(const ushort_t* __restrict__ Wih,
                             const ushort_t* __restrict__ Whh,
                             const ushort_t* __restrict__ bih,
                             const ushort_t* __restrict__ bhh,
                             const ushort_t* __restrict__ Wpost,
                             const ushort_t* __restrict__ bpost,
                             ushort_t* __restrict__ Wp,
                             float* __restrict__ bias2,
                             float* __restrict__ biaspost,
                             ushort_t* __restrict__ Wpb,
                             const int* __restrict__ flags)
{
    const int idx = blockIdx.x * 256 + threadIdx.x;
    const int fWih = flags[1], fWhh = flags[2], fbih = flags[3];
    const int fbhh = flags[4], fWpo = flags[5], fbpo = flags[6];

    if (idx < NGATE * KQ) {
        const int nn = idx >> 10;
        const int k  = idx & 1023;
        const int g  = (nn >> 4) & 3;
        const int n  = g * 512 + (nn >> 6) * 16 + (nn & 15);
        const int widx = n * KQ + k;
        float v = fWih ? ((const float*)Wih)[widx] : b2f(Wih[widx]);
        if (k < DIN) {
            int hidx = n * DIN + k;
            v += fWhh ? ((const float*)Whh)[hidx] : b2f(Whh[hidx]);
        }
        Wp[idx] = f2b(v);
    }
    if (idx < DOUT * KQ) {
        Wpb[idx] = fWpo ? f2b(((const float*)Wpost)[idx]) : Wpost[idx];
    }
    if (idx < NGATE) {
        const int g = (idx >> 4) & 3;
        const int n = g * 512 + (idx >> 6) * 16 + (idx & 15);
        float v1 = fbih ? ((const float*)bih)[n] : b2f(bih[n]);
        float v2 = fbhh ? ((const float*)bhh)[n] : b2f(bhh[n]);
        bias2[idx] = v1 + v2;
    }
    if (idx < DOUT) {
        biaspost[idx] = fbpo ? ((const float*)bpost)[idx] : b2f(bpost[idx]);
    }
}

// ---------------------------------------------------------------------------
// Step-0 cell from biases alone (q_star = 0, c = 0  =>  z = bih+bhh,
// identical for every graph). Replaces the t=0 GEMM and state zero-init.
// ---------------------------------------------------------------------------
__global__ void prep_h0(const ushort_t* __restrict__ bih,
                        const ushort_t* __restrict__ bhh,
                        float* __restrict__ c, float* __restrict__ H,
                        ushort_t* __restrict__ A, const int* __restrict__ flags)
{
    const int b   = blockIdx.x;
    const int tid = threadIdx.x;
    const int fbih = flags[3], fbhh = flags[4];
    for (int d = tid; d < DIN; d += 256) {
        auto ld = [&](int n) {
            float v1 = fbih ? ((const float*)bih)[n] : b2f(bih[n]);
            float v2 = fbhh ? ((const float*)bhh)[n] : b2f(bhh[n]);
            return v1 + v2;
        };
        float zi = ld(d);
        float zg = ld(2 * DIN + d);
        float zo = ld(3 * DIN + d);
        float c0 = fast_sigmoid(zi) * fast_tanh(zg);   // sig(zf)*c_prev = 0
        float h0 = fast_sigmoid(zo) * fast_tanh(c0);
        c[(size_t)b * DIN + d] = c0;
        H[(size_t)b * DIN + d] = h0;
        A[(size_t)b * KQ + d]       = f2b(h0);
        A[(size_t)b * KQ + DIN + d] = 0;
    }
}

// CSR offsets from sorted batch; handles int32 or int64 batch.
__global__ void prep_offsets(const int* __restrict__ batch, int* __restrict__ offs, int Nn)
{
    int n = blockIdx.x * 256 + threadIdx.x;
    if (n >= Nn) return;
    const bool is64 = batch[Nn - 1] < batch[Nn - 2];
    int cur  = is64 ? batch[2 * n] : batch[n];
    int prev = (n == 0) ? -1 : (is64 ? batch[2 * (n - 1)] : batch[n - 1]);
    for (int bb = prev + 1; bb <= cur; ++bb) offs[bb] = n;
    if (n == Nn - 1) {
        for (int bb = cur + 1; bb <= BGR; ++bb) offs[bb] = Nn;
    }
}

// ---------------------------------------------------------------------------
extern "C" void kernel_launch(void* const* d_in, const int* in_sizes, int n_in,
                              void* d_out, int out_size, void* d_ws, size_t ws_size,
                              hipStream_t stream)
{
    const ushort_t* x     = (const ushort_t*)d_in[0];
    const int*      batch = (const int*)d_in[1];
    const ushort_t* Wih   = (const ushort_t*)d_in[2];
    const ushort_t* Whh   = (const ushort_t*)d_in[3];
    const ushort_t* bih   = (const ushort_t*)d_in[4];
    const ushort_t* bhh   = (const ushort_t*)d_in[5];
    const ushort_t* Wpost = (const ushort_t*)d_in[6];
    const ushort_t* bpost = (const ushort_t*)d_in[7];
    const int Nn = in_sizes[1];
    const long long Tx = (long long)in_sizes[0];   // Nn * DIN elements

    char* p = (char*)d_ws;
    auto carve = [&](size_t bytes) -> void* {
        char* q = p;
        p += (bytes + 255) & ~(size_t)255;
        return (void*)q;
    };
    ushort_t* Wp       = (ushort_t*)carve((size_t)NGATE * KQ * 2);  // 4 MB
    ushort_t* Wpb      = (ushort_t*)carve((size_t)DOUT * KQ * 2);   // 1 MB
    float*    bias2    = (float*)carve((size_t)NGATE * 4);
    float*    biaspost = (float*)carve((size_t)DOUT * 4);
    float*    c        = (float*)carve((size_t)BGR * DIN * 4);      // 2 MB
    float*    H        = (float*)carve((size_t)BGR * DIN * 4);      // 2 MB
    ushort_t* A        = (ushort_t*)carve((size_t)BGR * KQ * 2);    // 2 MB
    int*      offs     = (int*)carve((size_t)(BGR + 1) * 4);
    int*      flags    = (int*)carve(16 * 4);
    size_t used = (size_t)(p - (char*)d_ws);
    const bool use_xb = (ws_size >= used + (size_t)Tx * 2 + 256);
    ushort_t* xb = use_xb ? (ushort_t*)carve((size_t)Tx * 2) : nullptr;

    probe_dtypes<<<1, 256, 0, stream>>>(x, Wih, Whh, bih, bhh, Wpost, bpost, flags);
    prep_weights<<<(NGATE * KQ) / 256, 256, 0, stream>>>(
        Wih, Whh, bih, bhh, Wpost, bpost, Wp, bias2, biaspost, Wpb, flags);
    prep_h0<<<BGR, 256, 0, stream>>>(bih, bhh, c, H, A, flags);
    prep_offsets<<<(Nn + 255) / 256, 256, 0, stream>>>(batch, offs, Nn);

    for (int t = 0; t < TSTEPS; ++t) {
        if (t > 0)
            gemm_cell<<<dim3(NGATE / 64, BGR / BM), 256, 0, stream>>>(
                A, Wp, bias2, c, H);
        if (use_xb) {
            if (t == 0)
                attn_step<1><<<BGR, 256, 0, stream>>>(xb, x, xb, offs, H, A, flags);
            else
                attn_step<0><<<BGR, 256, 0, stream>>>(xb, x, xb, offs, H, A, flags);
        } else {
            attn_step<2><<<BGR, 256, 0, stream>>>(x, x, nullptr, offs, H, A, flags);
        }
    }
    gemm_bt<1><<<dim3(DOUT / BN, BGR / BM), 256, 0, stream>>>(
        A, Wpb, biaspost, (float*)d_out, BGR, DOUT, KQ);
}